// Round 1
// baseline (384.977 us; speedup 1.0000x reference)
//
#include <hip/hip_runtime.h>
#include <math.h>
#include <cstdint>
#include <cstddef>

// Problem constants (fixed by the reference)
#define BB 32
#define TT 2048
#define HH 1024
#define UU 1024
#define NC 64          // chunks per batch
#define CT 32          // timesteps per chunk (NC*CT == TT)
#define NEG_BIG (-1e9f)

// ---------------------------------------------------------------------------
// Kernel 0: v[b,h] = sum_u Wa[h,u] * dec[b,u]
// One block per 4 h-rows. Stage the 4 Wa rows (16 KB) in LDS, then each of
// the 4 waves computes dots for 8 batches against the staged rows.
// ---------------------------------------------------------------------------
__global__ __launch_bounds__(256) void k_v(const float* __restrict__ Wa,
                                           const float* __restrict__ dec,
                                           float* __restrict__ v) {
    __shared__ float lds[4 * UU];          // 4 rows x 1024 floats = 16 KB
    const int tid = threadIdx.x;
    const int h0  = blockIdx.x * 4;

    const float4* Wa4  = reinterpret_cast<const float4*>(Wa + (size_t)h0 * UU);
    float4*       lds4 = reinterpret_cast<float4*>(lds);
    #pragma unroll
    for (int i = 0; i < 4; ++i)
        lds4[i * 256 + tid] = Wa4[i * 256 + tid];   // coalesced row loads
    __syncthreads();

    const int wid = tid >> 6, lane = tid & 63;
    for (int j = 0; j < 8; ++j) {
        const int b = wid * 8 + j;
        const float4* d4 = reinterpret_cast<const float4*>(dec + (size_t)b * UU);
        float4 dreg[4];
        #pragma unroll
        for (int k = 0; k < 4; ++k) dreg[k] = d4[k * 64 + lane];

        float p[4];
        #pragma unroll
        for (int r = 0; r < 4; ++r) {
            float acc = 0.f;
            #pragma unroll
            for (int k = 0; k < 4; ++k) {
                const float4 a = lds4[r * 256 + k * 64 + lane];
                acc += a.x * dreg[k].x + a.y * dreg[k].y +
                       a.z * dreg[k].z + a.w * dreg[k].w;
            }
            p[r] = acc;
        }
        #pragma unroll
        for (int r = 0; r < 4; ++r) {
            #pragma unroll
            for (int off = 32; off > 0; off >>= 1)
                p[r] += __shfl_xor(p[r], off, 64);
        }
        if (lane == 0) {
            #pragma unroll
            for (int r = 0; r < 4; ++r)
                v[(size_t)b * HH + h0 + r] = p[r];
        }
    }
}

// ---------------------------------------------------------------------------
// Kernel 1: flash-style single pass over enc_hs.
// Each wave owns one (b, chunk): computes score[t] = enc[b,t]·v[b] with a
// butterfly reduce, applies the mask, and maintains online-softmax state
// (m, l) plus a register-resident 1024-wide weighted context accumulator
// (16 floats/lane). Writes (m, l, ctx) partials to workspace.
// ---------------------------------------------------------------------------
__global__ __launch_bounds__(256) void k_flash(const float* __restrict__ enc,
                                               const int* __restrict__ mask,
                                               const float* __restrict__ v,
                                               float* __restrict__ pm,
                                               float* __restrict__ pl,
                                               float* __restrict__ pctx) {
    const int tid  = threadIdx.x;
    const int wid  = tid >> 6, lane = tid & 63;
    const int w    = blockIdx.x * 4 + wid;   // global wave id, 0..2047
    const int b    = w / NC;
    const int c    = w % NC;
    const int t0   = c * CT;

    // v[b] fragment: lane's h-slice is {(k*64+lane)*4 .. +3} for k=0..3
    const float4* v4 = reinterpret_cast<const float4*>(v + (size_t)b * HH);
    float4 vr[4];
    #pragma unroll
    for (int k = 0; k < 4; ++k) vr[k] = v4[k * 64 + lane];

    float m = -INFINITY, l = 0.f;
    float4 ctx[4];
    #pragma unroll
    for (int k = 0; k < 4; ++k) ctx[k] = make_float4(0.f, 0.f, 0.f, 0.f);

    const int*    mrow = mask + (size_t)b * TT + t0;
    const float4* erow = reinterpret_cast<const float4*>(
                             enc + ((size_t)b * TT + t0) * HH);

    #pragma unroll 4
    for (int t = 0; t < CT; ++t) {
        float4 e[4];
        #pragma unroll
        for (int k = 0; k < 4; ++k)
            e[k] = erow[(size_t)t * 256 + k * 64 + lane];   // coalesced 4 KB/row

        float p = 0.f;
        #pragma unroll
        for (int k = 0; k < 4; ++k)
            p += e[k].x * vr[k].x + e[k].y * vr[k].y +
                 e[k].z * vr[k].z + e[k].w * vr[k].w;
        #pragma unroll
        for (int off = 32; off > 0; off >>= 1)
            p += __shfl_xor(p, off, 64);

        const int   mv   = mrow[t];
        const float s    = mv ? p : NEG_BIG;     // additive-mask semantics
        const float keep = mv ? 1.f : 0.f;       // ref zeroes enc where masked

        const float mnew  = fmaxf(m, s);
        const float alpha = __expf(m - mnew);    // m=-inf first iter -> 0
        const float pe    = __expf(s - mnew);
        l = l * alpha + pe;
        const float pk = pe * keep;
        #pragma unroll
        for (int k = 0; k < 4; ++k) {
            ctx[k].x = ctx[k].x * alpha + pk * e[k].x;
            ctx[k].y = ctx[k].y * alpha + pk * e[k].y;
            ctx[k].z = ctx[k].z * alpha + pk * e[k].z;
            ctx[k].w = ctx[k].w * alpha + pk * e[k].w;
        }
        m = mnew;
    }

    if (lane == 0) { pm[w] = m; pl[w] = l; }
    float4* p4 = reinterpret_cast<float4*>(pctx + (size_t)w * HH);
    #pragma unroll
    for (int k = 0; k < 4; ++k) p4[k * 64 + lane] = ctx[k];
}

// ---------------------------------------------------------------------------
// Kernel 2: combine chunk partials.
// grid (B, H/256); thread owns one h. M/L recomputed per thread (64 L2-hot
// scalars), weights staged in LDS.
// ---------------------------------------------------------------------------
__global__ __launch_bounds__(256) void k_reduce(const float* __restrict__ pm,
                                                const float* __restrict__ pl,
                                                const float* __restrict__ pctx,
                                                float* __restrict__ out) {
    const int b = blockIdx.x;
    const int h = blockIdx.y * 256 + threadIdx.x;
    __shared__ float wsh[NC];

    float M = -INFINITY;
    for (int c = 0; c < NC; ++c) M = fmaxf(M, pm[b * NC + c]);
    float L = 0.f;
    for (int c = 0; c < NC; ++c) L += pl[b * NC + c] * __expf(pm[b * NC + c] - M);

    if (threadIdx.x < NC)
        wsh[threadIdx.x] = __expf(pm[b * NC + threadIdx.x] - M);
    __syncthreads();

    float acc = 0.f;
    for (int c = 0; c < NC; ++c)
        acc += wsh[c] * pctx[((size_t)b * NC + c) * HH + h];

    out[(size_t)b * HH + h] = acc / L;   // L >= 1 always (max chunk has pe=1)
}

// ---------------------------------------------------------------------------
extern "C" void kernel_launch(void* const* d_in, const int* in_sizes, int n_in,
                              void* d_out, int out_size, void* d_ws, size_t ws_size,
                              hipStream_t stream) {
    const float* enc  = (const float*)d_in[0];   // (B,T,H) fp32
    const float* dec  = (const float*)d_in[1];   // (B,H)   fp32
    const int*   mask = (const int*)  d_in[2];   // (B,T)   bool->int32
    const float* Wa   = (const float*)d_in[3];   // (H,U)   fp32
    float*       out  = (float*)d_out;           // (B,H)   fp32

    // Workspace layout (floats): v | pm | pl | pctx  (~8.6 MB total)
    float* ws   = (float*)d_ws;
    float* v    = ws;                            // B*H     = 32768
    float* pm   = v  + (size_t)BB * HH;          // B*NC    = 2048
    float* pl   = pm + (size_t)BB * NC;          // B*NC    = 2048
    float* pctx = pl + (size_t)BB * NC;          // B*NC*H  = 2097152

    k_v<<<HH / 4, 256, 0, stream>>>(Wa, dec, v);
    k_flash<<<(BB * NC) / 4, 256, 0, stream>>>(enc, mask, v, pm, pl, pctx);
    dim3 g2(BB, HH / 256);
    k_reduce<<<g2, 256, 0, stream>>>(pm, pl, pctx, out);
}

// Round 2
// 360.773 us; speedup vs baseline: 1.0671x; 1.0671x over previous
//
#include <hip/hip_runtime.h>
#include <math.h>
#include <cstdint>
#include <cstddef>

// Problem constants (fixed by the reference)
#define BB 32
#define TT 2048
#define HH 1024
#define UU 1024
#define NCH 128        // chunks per batch
#define CT 16          // timesteps per chunk (NCH*CT == TT)
#define NEG_BIG (-1e9f)

// ---------------------------------------------------------------------------
// Kernel 0: v[b,h] = sum_u Wa[h,u] * dec[b,u]
// One block per 4 h-rows. Stage the 4 Wa rows (16 KB) in LDS, then each of
// the 4 waves computes dots for 8 batches against the staged rows.
// ---------------------------------------------------------------------------
__global__ __launch_bounds__(256) void k_v(const float* __restrict__ Wa,
                                           const float* __restrict__ dec,
                                           float* __restrict__ v) {
    __shared__ float lds[4 * UU];          // 4 rows x 1024 floats = 16 KB
    const int tid = threadIdx.x;
    const int h0  = blockIdx.x * 4;

    const float4* Wa4  = reinterpret_cast<const float4*>(Wa + (size_t)h0 * UU);
    float4*       lds4 = reinterpret_cast<float4*>(lds);
    #pragma unroll
    for (int i = 0; i < 4; ++i)
        lds4[i * 256 + tid] = Wa4[i * 256 + tid];   // coalesced row loads
    __syncthreads();

    const int wid = tid >> 6, lane = tid & 63;
    for (int j = 0; j < 8; ++j) {
        const int b = wid * 8 + j;
        const float4* d4 = reinterpret_cast<const float4*>(dec + (size_t)b * UU);
        float4 dreg[4];
        #pragma unroll
        for (int k = 0; k < 4; ++k) dreg[k] = d4[k * 64 + lane];

        float p[4];
        #pragma unroll
        for (int r = 0; r < 4; ++r) {
            float acc = 0.f;
            #pragma unroll
            for (int k = 0; k < 4; ++k) {
                const float4 a = lds4[r * 256 + k * 64 + lane];
                acc += a.x * dreg[k].x + a.y * dreg[k].y +
                       a.z * dreg[k].z + a.w * dreg[k].w;
            }
            p[r] = acc;
        }
        #pragma unroll
        for (int r = 0; r < 4; ++r) {
            #pragma unroll
            for (int off = 32; off > 0; off >>= 1)
                p[r] += __shfl_xor(p[r], off, 64);
        }
        if (lane == 0) {
            #pragma unroll
            for (int r = 0; r < 4; ++r)
                v[(size_t)b * HH + h0 + r] = p[r];
        }
    }
}

// ---------------------------------------------------------------------------
// Kernel 1: flash-style single pass over enc_hs, CT=16 -> 4096 waves
// (16 waves/CU, vs 8 in R0). Masked timesteps: enc row is NOT loaded —
// exp(-1e9 - M) underflows to exactly 0 in fp32, identical to the ref's
// contribution; only the (m,l) online update runs (covers the all-masked
// row -> context 0 edge case exactly). The mask branch is wave-uniform.
// ---------------------------------------------------------------------------
__global__ __launch_bounds__(256, 4) void k_flash(const float* __restrict__ enc,
                                                  const int* __restrict__ mask,
                                                  const float* __restrict__ v,
                                                  float* __restrict__ pm,
                                                  float* __restrict__ pl,
                                                  float* __restrict__ pctx) {
    const int tid  = threadIdx.x;
    const int wid  = tid >> 6, lane = tid & 63;
    const int w    = blockIdx.x * 4 + wid;   // global wave id, 0..4095
    const int b    = w >> 7;                 // w / NCH
    const int c    = w & (NCH - 1);
    const int t0   = c * CT;

    // v[b] fragment: lane's h-slice is {(k*64+lane)*4 .. +3} for k=0..3
    const float4* v4 = reinterpret_cast<const float4*>(v + (size_t)b * HH);
    float4 vr[4];
    #pragma unroll
    for (int k = 0; k < 4; ++k) vr[k] = v4[k * 64 + lane];

    // Preload the chunk's mask row (wave-uniform values)
    const int* mrow = mask + (size_t)b * TT + t0;
    int mv[CT];
    #pragma unroll
    for (int t = 0; t < CT; ++t) mv[t] = mrow[t];

    float m = -INFINITY, l = 0.f;
    float4 ctx[4];
    #pragma unroll
    for (int k = 0; k < 4; ++k) ctx[k] = make_float4(0.f, 0.f, 0.f, 0.f);

    const float4* erow = reinterpret_cast<const float4*>(
                             enc + ((size_t)b * TT + t0) * HH);

    #pragma unroll 4
    for (int t = 0; t < CT; ++t) {
        if (mv[t]) {
            float4 e[4];
            #pragma unroll
            for (int k = 0; k < 4; ++k)
                e[k] = erow[(size_t)t * 256 + k * 64 + lane];  // coalesced 4 KB/row

            float p = 0.f;
            #pragma unroll
            for (int k = 0; k < 4; ++k)
                p += e[k].x * vr[k].x + e[k].y * vr[k].y +
                     e[k].z * vr[k].z + e[k].w * vr[k].w;
            #pragma unroll
            for (int off = 32; off > 0; off >>= 1)
                p += __shfl_xor(p, off, 64);

            const float mnew  = fmaxf(m, p);
            const float alpha = __expf(m - mnew);   // m=-inf first iter -> 0
            const float pe    = __expf(p - mnew);
            l = l * alpha + pe;
            #pragma unroll
            for (int k = 0; k < 4; ++k) {
                ctx[k].x = ctx[k].x * alpha + pe * e[k].x;
                ctx[k].y = ctx[k].y * alpha + pe * e[k].y;
                ctx[k].z = ctx[k].z * alpha + pe * e[k].z;
                ctx[k].w = ctx[k].w * alpha + pe * e[k].w;
            }
            m = mnew;
        } else {
            // score = -1e9 exactly; enc row contributes nothing to ctx
            // (if m == -inf, ctx is still 0, so ctx *= alpha is a no-op).
            const float mnew  = fmaxf(m, NEG_BIG);
            const float alpha = __expf(m - mnew);        // 0 (m=-inf) or 1
            l = l * alpha + __expf(NEG_BIG - mnew);      // 1 or underflow-0
            m = mnew;
        }
    }

    if (lane == 0) { pm[w] = m; pl[w] = l; }
    float4* p4 = reinterpret_cast<float4*>(pctx + (size_t)w * HH);
    #pragma unroll
    for (int k = 0; k < 4; ++k) p4[k * 64 + lane] = ctx[k];
}

// ---------------------------------------------------------------------------
// Kernel 2: combine chunk partials (stats folded in via LDS staging).
// grid (B, H/256); thread owns one h.
// ---------------------------------------------------------------------------
__global__ __launch_bounds__(256) void k_reduce(const float* __restrict__ pm,
                                                const float* __restrict__ pl,
                                                const float* __restrict__ pctx,
                                                float* __restrict__ out) {
    const int b = blockIdx.x;
    const int h = blockIdx.y * 256 + threadIdx.x;
    __shared__ float sm[NCH], sl[NCH];

    if (threadIdx.x < NCH) {
        sm[threadIdx.x] = pm[b * NCH + threadIdx.x];
        sl[threadIdx.x] = pl[b * NCH + threadIdx.x];
    }
    __syncthreads();

    float M = -INFINITY;
    #pragma unroll 8
    for (int c = 0; c < NCH; ++c) M = fmaxf(M, sm[c]);   // LDS broadcast reads
    float L = 0.f;
    #pragma unroll 8
    for (int c = 0; c < NCH; ++c) L += sl[c] * __expf(sm[c] - M);

    float acc = 0.f;
    #pragma unroll 8
    for (int c = 0; c < NCH; ++c)
        acc += __expf(sm[c] - M) * pctx[((size_t)b * NCH + c) * HH + h];

    out[(size_t)b * HH + h] = acc / L;   // L >= 1 (max chunk contributes pe=1)
}

// ---------------------------------------------------------------------------
extern "C" void kernel_launch(void* const* d_in, const int* in_sizes, int n_in,
                              void* d_out, int out_size, void* d_ws, size_t ws_size,
                              hipStream_t stream) {
    const float* enc  = (const float*)d_in[0];   // (B,T,H) fp32
    const float* dec  = (const float*)d_in[1];   // (B,H)   fp32
    const int*   mask = (const int*)  d_in[2];   // (B,T)   bool->int32
    const float* Wa   = (const float*)d_in[3];   // (H,U)   fp32
    float*       out  = (float*)d_out;           // (B,H)   fp32

    // Workspace layout (floats): v | pm | pl | pctx  (~16.2 MB total)
    float* ws   = (float*)d_ws;
    float* v    = ws;                            // B*H      = 32768
    float* pm   = v  + (size_t)BB * HH;          // B*NCH    = 4096
    float* pl   = pm + (size_t)BB * NCH;         // B*NCH    = 4096
    float* pctx = pl + (size_t)BB * NCH;         // B*NCH*H  = 4194304

    k_v<<<HH / 4, 256, 0, stream>>>(Wa, dec, v);
    k_flash<<<(BB * NCH) / 4, 256, 0, stream>>>(enc, mask, v, pm, pl, pctx);
    dim3 g2(BB, HH / 256);
    k_reduce<<<g2, 256, 0, stream>>>(pm, pl, pctx, out);
}

// Round 3
// 347.287 us; speedup vs baseline: 1.1085x; 1.0388x over previous
//
#include <hip/hip_runtime.h>
#include <math.h>
#include <cstdint>
#include <cstddef>

// Problem constants (fixed by the reference)
#define BB 32
#define TT 2048
#define HH 1024
#define UU 1024
#define NBK 32         // chunk-blocks per batch
#define BT 64          // timesteps per block (NBK*BT == TT)
#define WT 16          // timesteps per wave (4 waves * WT == BT)
#define NEG_BIG (-1e9f)

// ---------------------------------------------------------------------------
// Kernel 0: v[b,h] = sum_u Wa[h,u] * dec[b,u]
// One block per 4 h-rows. Stage the 4 Wa rows (16 KB) in LDS, then each of
// the 4 waves computes dots for 8 batches against the staged rows.
// ---------------------------------------------------------------------------
__global__ __launch_bounds__(256) void k_v(const float* __restrict__ Wa,
                                           const float* __restrict__ dec,
                                           float* __restrict__ v) {
    __shared__ float lds[4 * UU];          // 4 rows x 1024 floats = 16 KB
    const int tid = threadIdx.x;
    const int h0  = blockIdx.x * 4;

    const float4* Wa4  = reinterpret_cast<const float4*>(Wa + (size_t)h0 * UU);
    float4*       lds4 = reinterpret_cast<float4*>(lds);
    #pragma unroll
    for (int i = 0; i < 4; ++i)
        lds4[i * 256 + tid] = Wa4[i * 256 + tid];   // coalesced row loads
    __syncthreads();

    const int wid = tid >> 6, lane = tid & 63;
    for (int j = 0; j < 8; ++j) {
        const int b = wid * 8 + j;
        const float4* d4 = reinterpret_cast<const float4*>(dec + (size_t)b * UU);
        float4 dreg[4];
        #pragma unroll
        for (int k = 0; k < 4; ++k) dreg[k] = d4[k * 64 + lane];

        float p[4];
        #pragma unroll
        for (int r = 0; r < 4; ++r) {
            float acc = 0.f;
            #pragma unroll
            for (int k = 0; k < 4; ++k) {
                const float4 a = lds4[r * 256 + k * 64 + lane];
                acc += a.x * dreg[k].x + a.y * dreg[k].y +
                       a.z * dreg[k].z + a.w * dreg[k].w;
            }
            p[r] = acc;
        }
        #pragma unroll
        for (int r = 0; r < 4; ++r) {
            #pragma unroll
            for (int off = 32; off > 0; off >>= 1)
                p[r] += __shfl_xor(p[r], off, 64);
        }
        if (lane == 0) {
            #pragma unroll
            for (int r = 0; r < 4; ++r)
                v[(size_t)b * HH + h0 + r] = p[r];
        }
    }
}

// ---------------------------------------------------------------------------
// Kernel 1: flash-style single pass over enc_hs.
// Grid = B*NBK blocks; each block owns 64 consecutive t (good L2 locality),
// its 4 waves take 16 t each with register-resident online softmax, then the
// block merges the 4 wave states in LDS (max-rescaled, exact fp32 semantics)
// and writes ONE partial per block: pctx shrinks 16 MB -> 4 MB vs R2.
// Masked t: enc row never loaded (exp(-1e9-M) underflows to exactly 0, and
// ref zeroes enc for masked t); all-masked edge case stays exact.
// ---------------------------------------------------------------------------
__global__ __launch_bounds__(256, 4) void k_flash(const float* __restrict__ enc,
                                                  const int* __restrict__ mask,
                                                  const float* __restrict__ v,
                                                  float* __restrict__ pm,
                                                  float* __restrict__ pl,
                                                  float* __restrict__ pctx) {
    const int tid  = threadIdx.x;
    const int wid  = tid >> 6, lane = tid & 63;
    const int bk   = blockIdx.x;             // 0..B*NBK-1
    const int b    = bk >> 5;                // bk / NBK
    const int c    = bk & (NBK - 1);
    const int t0   = c * BT + wid * WT;

    // v[b] fragment: lane's h-slice is {(k*64+lane)*4 .. +3} for k=0..3
    const float4* v4 = reinterpret_cast<const float4*>(v + (size_t)b * HH);
    float4 vr[4];
    #pragma unroll
    for (int k = 0; k < 4; ++k) vr[k] = v4[k * 64 + lane];

    // Preload the wave's mask row (wave-uniform values)
    const int* mrow = mask + (size_t)b * TT + t0;
    int mv[WT];
    #pragma unroll
    for (int t = 0; t < WT; ++t) mv[t] = mrow[t];

    float m = -INFINITY, l = 0.f;
    float4 ctx[4];
    #pragma unroll
    for (int k = 0; k < 4; ++k) ctx[k] = make_float4(0.f, 0.f, 0.f, 0.f);

    const float4* erow = reinterpret_cast<const float4*>(
                             enc + ((size_t)b * TT + t0) * HH);

    #pragma unroll 4
    for (int t = 0; t < WT; ++t) {
        if (mv[t]) {                                   // wave-uniform branch
            float4 e[4];
            #pragma unroll
            for (int k = 0; k < 4; ++k)
                e[k] = erow[(size_t)t * 256 + k * 64 + lane];  // 4 KB/row coalesced

            float p = 0.f;
            #pragma unroll
            for (int k = 0; k < 4; ++k)
                p += e[k].x * vr[k].x + e[k].y * vr[k].y +
                     e[k].z * vr[k].z + e[k].w * vr[k].w;
            #pragma unroll
            for (int off = 32; off > 0; off >>= 1)
                p += __shfl_xor(p, off, 64);

            const float mnew  = fmaxf(m, p);
            const float alpha = __expf(m - mnew);      // m=-inf first iter -> 0
            const float pe    = __expf(p - mnew);
            l = l * alpha + pe;
            #pragma unroll
            for (int k = 0; k < 4; ++k) {
                ctx[k].x = ctx[k].x * alpha + pe * e[k].x;
                ctx[k].y = ctx[k].y * alpha + pe * e[k].y;
                ctx[k].z = ctx[k].z * alpha + pe * e[k].z;
                ctx[k].w = ctx[k].w * alpha + pe * e[k].w;
            }
            m = mnew;
        } else {
            // score = -1e9 exactly; enc contributes nothing to ctx.
            const float mnew  = fmaxf(m, NEG_BIG);
            const float alpha = __expf(m - mnew);      // 0 (m=-inf) or 1
            l = l * alpha + __expf(NEG_BIG - mnew);    // 1 or underflow-0
            m = mnew;
        }
    }

    // ---- block-level combine of the 4 wave states (LDS, exact) ----
    __shared__ float4 sctx[4 * 256];                   // 16 KB
    __shared__ float  sm[4], sl[4];
    #pragma unroll
    for (int k = 0; k < 4; ++k)
        sctx[wid * 256 + k * 64 + lane] = ctx[k];
    if (lane == 0) { sm[wid] = m; sl[wid] = l; }
    __syncthreads();

    const float M  = fmaxf(fmaxf(sm[0], sm[1]), fmaxf(sm[2], sm[3]));  // >= -1e9
    const float a0 = __expf(sm[0] - M), a1 = __expf(sm[1] - M);
    const float a2 = __expf(sm[2] - M), a3 = __expf(sm[3] - M);
    const float L  = sl[0] * a0 + sl[1] * a1 + sl[2] * a2 + sl[3] * a3;

    const float4 x0 = sctx[tid], x1 = sctx[256 + tid];
    const float4 x2 = sctx[512 + tid], x3 = sctx[768 + tid];
    float4 r;
    r.x = a0 * x0.x + a1 * x1.x + a2 * x2.x + a3 * x3.x;
    r.y = a0 * x0.y + a1 * x1.y + a2 * x2.y + a3 * x3.y;
    r.z = a0 * x0.z + a1 * x1.z + a2 * x2.z + a3 * x3.z;
    r.w = a0 * x0.w + a1 * x1.w + a2 * x2.w + a3 * x3.w;

    reinterpret_cast<float4*>(pctx + (size_t)bk * HH)[tid] = r;
    if (tid == 0) { pm[bk] = M; pl[bk] = L; }
}

// ---------------------------------------------------------------------------
// Kernel 2: combine the NBK block partials per batch.
// grid (B, H/256); thread owns one h. Only 4 MB of pctx to read now.
// ---------------------------------------------------------------------------
__global__ __launch_bounds__(256) void k_reduce(const float* __restrict__ pm,
                                                const float* __restrict__ pl,
                                                const float* __restrict__ pctx,
                                                float* __restrict__ out) {
    const int b = blockIdx.x;
    const int h = blockIdx.y * 256 + threadIdx.x;
    __shared__ float sm[NBK], sl[NBK];

    if (threadIdx.x < NBK) {
        sm[threadIdx.x] = pm[b * NBK + threadIdx.x];
        sl[threadIdx.x] = pl[b * NBK + threadIdx.x];
    }
    __syncthreads();

    float M = -INFINITY;
    #pragma unroll
    for (int c = 0; c < NBK; ++c) M = fmaxf(M, sm[c]);   // LDS broadcast reads

    float L = 0.f, acc = 0.f;
    #pragma unroll 4
    for (int c = 0; c < NBK; ++c) {
        const float e = __expf(sm[c] - M);
        L   += sl[c] * e;
        acc += e * pctx[((size_t)b * NBK + c) * HH + h];
    }

    out[(size_t)b * HH + h] = acc / L;   // L >= 1 (max chunk contributes pe=1)
}

// ---------------------------------------------------------------------------
extern "C" void kernel_launch(void* const* d_in, const int* in_sizes, int n_in,
                              void* d_out, int out_size, void* d_ws, size_t ws_size,
                              hipStream_t stream) {
    const float* enc  = (const float*)d_in[0];   // (B,T,H) fp32
    const float* dec  = (const float*)d_in[1];   // (B,H)   fp32
    const int*   mask = (const int*)  d_in[2];   // (B,T)   bool->int32
    const float* Wa   = (const float*)d_in[3];   // (H,U)   fp32
    float*       out  = (float*)d_out;           // (B,H)   fp32

    // Workspace layout (floats): v | pm | pl | pctx  (~4.3 MB total)
    float* ws   = (float*)d_ws;
    float* v    = ws;                            // B*H      = 32768
    float* pm   = v  + (size_t)BB * HH;          // B*NBK    = 1024
    float* pl   = pm + (size_t)BB * NBK;         // B*NBK    = 1024
    float* pctx = pl + (size_t)BB * NBK;         // B*NBK*H  = 1048576

    k_v<<<HH / 4, 256, 0, stream>>>(Wa, dec, v);
    k_flash<<<BB * NBK, 256, 0, stream>>>(enc, mask, v, pm, pl, pctx);
    dim3 g2(BB, HH / 256);
    k_reduce<<<g2, 256, 0, stream>>>(pm, pl, pctx, out);
}